// Round 11
// baseline (778.795 us; speedup 1.0000x reference)
//
#include <hip/hip_runtime.h>
#include <hip/hip_bf16.h>

// Problem constants
static constexpr int B_  = 16384;
static constexpr int D_  = 2048;
static constexpr int S_  = 512;
static constexpr int E_  = 8;
static constexpr int H1_ = 1024;
static constexpr int H2_ = 512;
static constexpr float EPS_ = 1e-5f;

typedef __bf16 bf16x8 __attribute__((ext_vector_type(8)));
typedef float  f32x4  __attribute__((ext_vector_type(4)));
typedef float  f32x16 __attribute__((ext_vector_type(16)));

static __device__ __forceinline__ unsigned short f2bf(float f) {
    unsigned u = __float_as_uint(f);
    unsigned r = (u + 0x7fffu + ((u >> 16) & 1u)) >> 16;   // RTNE
    return (unsigned short)r;
}

// ---------------- prepass kernels (verified R1/R2) ----------------

__global__ void cvt_bf16_kernel(const float* __restrict__ in, ushort* __restrict__ out, long n) {
    long i = ((long)blockIdx.x * blockDim.x + threadIdx.x) * 4;
    long stride = (long)gridDim.x * blockDim.x * 4;
    for (; i < n; i += stride) {
        float4 v = *(const float4*)(in + i);
        ushort4 o;
        o.x = f2bf(v.x); o.y = f2bf(v.y); o.z = f2bf(v.z); o.w = f2bf(v.w);
        *(ushort4*)(out + i) = o;
    }
}

// in: [E][R][C] f32  ->  out: [E][C][R] bf16
__global__ void transpose_cvt_kernel(const float* __restrict__ in, ushort* __restrict__ out,
                                     int R, int C) {
    __shared__ float t[64][65];
    int nbr = R >> 6, nbc = C >> 6;
    int bid = blockIdx.x;
    int e = bid / (nbr * nbc);
    int rem = bid % (nbr * nbc);
    int br = (rem / nbc) << 6, bc = (rem % nbc) << 6;
    const float* ip = in + (size_t)e * R * C;
    ushort* op = out + (size_t)e * R * C;
    int tcol = (threadIdx.x & 15) * 4;
    int trow = threadIdx.x >> 4;
#pragma unroll
    for (int p = 0; p < 4; p++) {
        int r = trow + p * 16;
        float4 v = *(const float4*)(ip + (size_t)(br + r) * C + bc + tcol);
        t[r][tcol + 0] = v.x; t[r][tcol + 1] = v.y; t[r][tcol + 2] = v.z; t[r][tcol + 3] = v.w;
    }
    __syncthreads();
#pragma unroll
    for (int p = 0; p < 4; p++) {
        int c = trow + p * 16;
        ushort4 o;
        o.x = f2bf(t[tcol + 0][c]);
        o.y = f2bf(t[tcol + 1][c]);
        o.z = f2bf(t[tcol + 2][c]);
        o.w = f2bf(t[tcol + 3][c]);
        *(ushort4*)(op + (size_t)(bc + c) * R + br + tcol) = o;
    }
}

__global__ void fold_bn_kernel(const float* __restrict__ gamma, const float* __restrict__ beta,
                               const float* __restrict__ mean, const float* __restrict__ var,
                               const float* __restrict__ bias,
                               float* __restrict__ Sv, float* __restrict__ Tv, int n) {
    int i = blockIdx.x * 256 + threadIdx.x;
    if (i < n) {
        float s = gamma[i] * rsqrtf(var[i] + EPS_);
        Sv[i] = s;
        Tv[i] = (bias[i] - mean[i]) * s + beta[i];
    }
}

__global__ void gate_kernel(const float* __restrict__ side, const float* __restrict__ Wg,
                            const float* __restrict__ bg, float* __restrict__ gate) {
    int wid = threadIdx.x >> 6, lane = threadIdx.x & 63;
    int b = blockIdx.x * 4 + wid;
    const float* sp = side + (size_t)b * S_ + lane * 8;
    float4 v0 = *(const float4*)sp;
    float4 v1 = *(const float4*)(sp + 4);
    float sv[8] = {v0.x, v0.y, v0.z, v0.w, v1.x, v1.y, v1.z, v1.w};
    float acc[E_] = {0,0,0,0,0,0,0,0};
    const float* wrow = Wg + (size_t)(lane * 8) * E_;
#pragma unroll
    for (int j = 0; j < 8; j++) {
        float4 w0 = *(const float4*)(wrow + j * E_);
        float4 w1 = *(const float4*)(wrow + j * E_ + 4);
        acc[0] += sv[j] * w0.x; acc[1] += sv[j] * w0.y;
        acc[2] += sv[j] * w0.z; acc[3] += sv[j] * w0.w;
        acc[4] += sv[j] * w1.x; acc[5] += sv[j] * w1.y;
        acc[6] += sv[j] * w1.z; acc[7] += sv[j] * w1.w;
    }
#pragma unroll
    for (int off = 32; off; off >>= 1)
#pragma unroll
        for (int e = 0; e < E_; e++) acc[e] += __shfl_xor(acc[e], off, 64);
    float m = -1e30f;
#pragma unroll
    for (int e = 0; e < E_; e++) { acc[e] += bg[e]; m = fmaxf(m, acc[e]); }
    float s = 0.f;
#pragma unroll
    for (int e = 0; e < E_; e++) { acc[e] = __expf(acc[e] - m); s += acc[e]; }
    float inv = 1.f / s;
    if (lane < E_) gate[(size_t)b * E_ + lane] = acc[lane] * inv;
}

// ---------------- shared GEMM helpers ----------------

__device__ __forceinline__ void g2lds16(const void* g, void* l) {
    __builtin_amdgcn_global_load_lds((const __attribute__((address_space(1))) unsigned int*)g,
                                     (__attribute__((address_space(3))) unsigned int*)l,
                                     16, 0, 0);
}

#define BAR()      asm volatile("s_barrier" ::: "memory")
#define WAITVM(n)  asm volatile("s_waitcnt vmcnt(" #n ")" ::: "memory")
#define MFMA(a,b,c) __builtin_amdgcn_mfma_f32_16x16x32_bf16((a),(b),(c),0,0,0)
#define MFMA32(a,b,c) __builtin_amdgcn_mfma_f32_32x32x16_bf16((a),(b),(c),0,0,0)

// ---------------- GEMM1: 256x256, R10 schedule, 32x32x16 MFMA ----------------
// LDS map (160 KiB): B bufs at {0,32768,65536} (triple, rotating);
//                    A bufs at {98304,131072} (double, bi = t&1).
// Swizzle: LDS[row][x] = global[row][x ^ ((row&7)<<4)] (both-sides, rule #21).
// Schedule (verified R10): tile t reads A buf bi / B buf bCur(t%3);
//   P0 stages A(t+1)->bi^1, P1/P2 stage B(t+2)->bN2; boundary vmcnt(4)+BAR
//   (A(t+1) retired, B(t+2)'s 4 in flight); vmcnt(0) only at t==NT-2.
// R11: compute in 32x32x16 (2495 TF ceiling vs 2075; half the MFMA instrs).
//   4 phases = 4 ks-steps (K=16 each); frags read one ks ahead (ping-pong).
//   Frag mapping [m74/m101, HW-verified]: A/B row=lane&31, k8=(lane>>5);
//   C/D col=lane&31, row=(reg&3)+8*(reg>>2)+4*(lane>>5).

template<int EPI>
__global__ __launch_bounds__(512, 2)
void gemm8(const ushort* __restrict__ A, const ushort* __restrict__ Bt, long aBatch,
           const float* __restrict__ Sv, const float* __restrict__ Tv,
           ushort* __restrict__ hout, float* __restrict__ outp, const float* __restrict__ gate,
           int M, int N, int K, int tilesN, int tilesM)
{
    extern __shared__ char smem[];

    const int NT  = K >> 6;
    const int tpe = tilesM * tilesN;

    const int nwg = gridDim.x, per = nwg >> 3;
    const int b0  = blockIdx.x;
    const int bid = (b0 & 7) * per + (b0 >> 3);

    const int e   = bid / tpe;
    const int rem = bid % tpe;
    const int tm  = rem / tilesN, tn = rem % tilesN;

    const char* aBase = (const char*)(A + (size_t)e * aBatch + (size_t)tm * 256 * K);
    const char* bBase = (const char*)(Bt + (size_t)e * N * K + (size_t)tn * 256 * K);
    const size_t rowB = (size_t)K * 2;
    const size_t half2 = 64 * rowB;
    const size_t half1 = 128 * rowB;

    const int tid = threadIdx.x, w = tid >> 6, lane = tid & 63;
    const int wm = w >> 2, wn = w & 3;

    const int srow = tid >> 3;
    const int scol_sw = ((tid & 7) * 16) ^ ((srow & 7) << 4);
    const int ldsW = w * 1024;

    // 32x32 fragment lane constants: row = base + (lane&31); byte = (ks*32 + (lane>>5)*16) ^ swz
    const int l31 = lane & 31;
    const int swz = (lane & 7) << 4;
    const int hi16 = (lane >> 5) * 16;
    int cks[4];
#pragma unroll
    for (int ks = 0; ks < 4; ++ks) cks[ks] = (ks * 32 + hi16) ^ swz;

    // per-lane read bases; {bi/bCur, mt/nt} variation via offsets
    const char* rdAk[4];
    const char* rdBk[4];
#pragma unroll
    for (int ks = 0; ks < 4; ++ks) {
        rdAk[ks] = smem + 98304 + (wm * 128 + l31) * 128 + cks[ks];
        rdBk[ks] = smem + (wn * 64 + l31) * 128 + cks[ks];
    }

#define STG(gp, ldsoff) do { \
        g2lds16((gp), smem + (ldsoff)); \
        g2lds16((gp) + half2, smem + (ldsoff) + 8192); } while (0)

    const char* ga = aBase + (size_t)srow * rowB + scol_sw;
    const char* gb = bBase + (size_t)srow * rowB + scol_sw;

    f32x16 acc[4][2] = {};          // [mt][nt], 32x32 tiles; per-wave 128x64
    bf16x8 fA[2][4], fB[2][2];      // ping-pong fragment sets by ks parity

    // rotating B buffer offsets: bCur = t%3, bN1 = (t+1)%3, bN2 = (t+2)%3
    int bCur = 0, bN1 = 32768, bN2 = 65536;

    // prologue: A(0)->A0, B(0)->B0, B(1)->B1; wait A(0),B(0) (4 newest = B(1))
    STG(ga,                98304 + 0 + 0     + ldsW);
    STG(ga + half1,        98304 + 0 + 16384 + ldsW);
    STG(gb,                0     + 0     + ldsW);
    STG(gb + half1,        0     + 16384 + ldsW);
    STG(gb + 128,          32768 + 0     + ldsW);
    STG(gb + half1 + 128,  32768 + 16384 + ldsW);
    WAITVM(4);
    BAR();

    // refill ks0 fragments of tile 0 (buffer 0)
#pragma unroll
    for (int mt = 0; mt < 4; ++mt) fA[0][mt] = *(const bf16x8*)(rdAk[0] + mt * 4096);
#pragma unroll
    for (int nt = 0; nt < 2; ++nt) fB[0][nt] = *(const bf16x8*)(rdBk[0] + nt * 4096);

    // staging pointers: A -> tile t+1; B -> tile t+2 (advance 128 B/tile)
    const char* spA0 = ga + 128;
    const char* spA1 = ga + half1 + 128;
    const char* spB0 = gb + 256;
    const char* spB1 = gb + half1 + 256;

#pragma unroll 2
    for (int t = 0; t < NT; ++t) {
        const int bi    = t & 1;
        const int oRA   = bi * 32768;               // A read offset
        const int oRAN  = (bi ^ 1) * 32768;         // next-tile A read offset
        const int oSA   = 98304 + (bi ^ 1) * 32768; // A stage base
        const bool moreA = (t < NT - 1);
        const bool moreB = (t < NT - 2);

        // ---- P0: read ks1 frags; stage A(t+1) (4 loads, FIRST); MFMA ks0 (8)
#pragma unroll
        for (int mt = 0; mt < 4; ++mt) fA[1][mt] = *(const bf16x8*)(rdAk[1] + oRA + mt * 4096);
#pragma unroll
        for (int nt = 0; nt < 2; ++nt) fB[1][nt] = *(const bf16x8*)(rdBk[1] + bCur + nt * 4096);
        if (moreA) {
            STG(spA0, oSA + 0 + ldsW);
            STG(spA1, oSA + 16384 + ldsW);
        }
        __builtin_amdgcn_s_setprio(1);
#pragma unroll
        for (int mt = 0; mt < 4; ++mt)
#pragma unroll
            for (int nt = 0; nt < 2; ++nt)
                acc[mt][nt] = MFMA32(fA[0][mt], fB[0][nt], acc[mt][nt]);
        __builtin_amdgcn_s_setprio(0);

        // ---- P1: read ks2 frags; stage B(t+2) lo; MFMA ks1 (8)
#pragma unroll
        for (int mt = 0; mt < 4; ++mt) fA[0][mt] = *(const bf16x8*)(rdAk[2] + oRA + mt * 4096);
#pragma unroll
        for (int nt = 0; nt < 2; ++nt) fB[0][nt] = *(const bf16x8*)(rdBk[2] + bCur + nt * 4096);
        if (moreB) STG(spB0, bN2 + 0 + ldsW);
        __builtin_amdgcn_s_setprio(1);
#pragma unroll
        for (int mt = 0; mt < 4; ++mt)
#pragma unroll
            for (int nt = 0; nt < 2; ++nt)
                acc[mt][nt] = MFMA32(fA[1][mt], fB[1][nt], acc[mt][nt]);
        __builtin_amdgcn_s_setprio(0);

        // ---- P2: read ks3 frags; stage B(t+2) hi; MFMA ks2 (8)
#pragma unroll
        for (int mt = 0; mt < 4; ++mt) fA[1][mt] = *(const bf16x8*)(rdAk[3] + oRA + mt * 4096);
#pragma unroll
        for (int nt = 0; nt < 2; ++nt) fB[1][nt] = *(const bf16x8*)(rdBk[3] + bCur + nt * 4096);
        if (moreB) STG(spB1, bN2 + 16384 + ldsW);
        __builtin_amdgcn_s_setprio(1);
#pragma unroll
        for (int mt = 0; mt < 4; ++mt)
#pragma unroll
            for (int nt = 0; nt < 2; ++nt)
                acc[mt][nt] = MFMA32(fA[0][mt], fB[0][nt], acc[mt][nt]);
        __builtin_amdgcn_s_setprio(0);

        // ---- P3: MFMA ks3 (8)
        __builtin_amdgcn_s_setprio(1);
#pragma unroll
        for (int mt = 0; mt < 4; ++mt)
#pragma unroll
            for (int nt = 0; nt < 2; ++nt)
                acc[mt][nt] = MFMA32(fA[1][mt], fB[1][nt], acc[mt][nt]);
        __builtin_amdgcn_s_setprio(0);

        // ---- boundary: counted vmcnt — A(t+1) retired, B(t+2)'s 4 stay in flight
        if (moreA) {
            if (moreB) { WAITVM(4); } else { WAITVM(0); }
            BAR();
            // refill ks0 fragments of tile t+1
#pragma unroll
            for (int mt = 0; mt < 4; ++mt) fA[0][mt] = *(const bf16x8*)(rdAk[0] + oRAN + mt * 4096);
#pragma unroll
            for (int nt = 0; nt < 2; ++nt) fB[0][nt] = *(const bf16x8*)(rdBk[0] + bN1 + nt * 4096);
        }

        spA0 += 128; spA1 += 128; spB0 += 128; spB1 += 128;
        const int tb = bCur; bCur = bN1; bN1 = bN2; bN2 = tb;
    }

    // epilogue: 32x32 C/D layout col = lane&31, row = (reg&3)+8*(reg>>2)+4*(lane>>5)
    if (EPI == 1) {
        const int rb32 = tm * 256 + wm * 128 + 4 * (lane >> 5);
        const int cb32 = tn * 256 + wn * 64 + l31;
#pragma unroll
        for (int nt = 0; nt < 2; ++nt) {
            const int col = cb32 + nt * 32;
            const float s = Sv[e * N + col];
            const float tt = Tv[e * N + col];
#pragma unroll
            for (int mt = 0; mt < 4; ++mt) {
                f32x16 v = acc[mt][nt];
#pragma unroll
                for (int r = 0; r < 16; ++r) {
                    const int row = rb32 + mt * 32 + (r & 3) + 8 * (r >> 2);
                    float x = v[r] * s + tt;
                    x = x > 0.f ? x : 0.f;
                    hout[((size_t)e * M + row) * N + col] = f2bf(x);
                }
            }
        }
    }
#undef STG
}

// ---------------- GEMM2e: expert-loop, TRIPLE-buffered counted-vmcnt pipeline ----------------
// (verified R9/R10) out[b][n] = sum_e gate[b][e] * relu(bn2_e( h[e][b] @ W2T[e][n] ))
// BM=128, BN=256; grid = 256 blocks = 1/CU. Flat tau over (e,kt), NT=128.
// LDS 144 KiB: B bufs {0,32768,65536}; A bufs {98304,114688,131072}.

__global__ __launch_bounds__(512, 2)
void gemm2e(const ushort* __restrict__ H, const ushort* __restrict__ W2T,
            const float* __restrict__ Sv, const float* __restrict__ Tv,
            const float* __restrict__ gate, float* __restrict__ outp)
{
    extern __shared__ char smem[];

    const int b0 = blockIdx.x;
    const int bid = (b0 & 7) * 32 + (b0 >> 3);
    const int tm = bid >> 1, tn = bid & 1;

    const size_t rowB  = (size_t)H1_ * 2;
    const size_t strAE = (size_t)B_ * H1_ * 2;
    const size_t strBE = (size_t)H2_ * H1_ * 2;
    const size_t half2 = 64 * rowB;
    const size_t halfB = 128 * rowB;

    const int tid = threadIdx.x, w = tid >> 6, lane = tid & 63;
    const int wm = w >> 2, wn = w & 3;

    const int srow = tid >> 3;
    const int scol_sw = ((tid & 7) * 16) ^ ((srow & 7) << 4);
    const int ldsW = w * 1024;

    const int lr = lane & 15;
    const int cks0 = ((lane >> 4) * 16) ^ ((lane & 7) << 4);
    const int cks1 = (64 + (lane >> 4) * 16) ^ ((lane & 7) << 4);
    const char* rdA0 = smem + (wm * 64 + lr) * 128 + cks0;
    const char* rdA1 = smem + (wm * 64 + lr) * 128 + cks1;
    const char* rdB0 = smem + (wn * 64 + lr) * 128 + cks0;
    const char* rdB1 = smem + (wn * 64 + lr) * 128 + cks1;

    const char* ga = (const char*)H + (size_t)tm * 128 * rowB + (size_t)srow * rowB + scol_sw;
    const char* gb = (const char*)W2T + (size_t)tn * 256 * rowB + (size_t)srow * rowB + scol_sw;

#define STG6(gAp, gBp, aOff, bOff) do { \
        g2lds16((gAp),                 smem + (aOff) + 0     + ldsW); \
        g2lds16((gAp) + half2,         smem + (aOff) + 8192  + ldsW); \
        g2lds16((gBp),                 smem + (bOff) + 0     + ldsW); \
        g2lds16((gBp) + half2,         smem + (bOff) + 8192  + ldsW); \
        g2lds16((gBp) + halfB,         smem + (bOff) + 16384 + ldsW); \
        g2lds16((gBp) + halfB + half2, smem + (bOff) + 24576 + ldsW); } while (0)

    f32x4 acc[4][4] = {};
    f32x4 oacc[4][4] = {};
    bf16x8 a0[4], a1[4], b0v[4], b1v[4];

    int aCur = 98304, aN1 = 114688, aN2 = 131072;
    int bCur = 0,     bN1 = 32768,  bN2 = 65536;

    STG6(ga, gb, aCur, bCur);
    STG6(ga + 128, gb + 128, aN1, bN1);
    WAITVM(6);
    BAR();

#pragma unroll
    for (int mf = 0; mf < 4; ++mf) a0[mf] = *(const bf16x8*)(rdA0 + aCur + mf * 2048);
#pragma unroll
    for (int nf = 0; nf < 4; ++nf) b0v[nf] = *(const bf16x8*)(rdB0 + bCur + nf * 2048);

    const int rbase = tm * 128 + wm * 64 + (lane >> 4) * 4;
    const int cbase = tn * 256 + wn * 64 + lr;

    for (int t = 0; t < 128; ++t) {
        const int t2 = t + 2;
        const bool moreS = (t2 < 128);
        const bool moreT = (t < 127);

        const char* gA2 = ga + (size_t)(t2 >> 4) * strAE + (t2 & 15) * 128;
        const char* gB2 = gb + (size_t)(t2 >> 4) * strBE + (t2 & 15) * 128;

        // ---- P0: prefetch ks1 frags (cur); stage (t+2) -> n2; MFMA ks0 (16)
#pragma unroll
        for (int mf = 0; mf < 4; ++mf) a1[mf] = *(const bf16x8*)(rdA1 + aCur + mf * 2048);
#pragma unroll
        for (int nf = 0; nf < 4; ++nf) b1v[nf] = *(const bf16x8*)(rdB1 + bCur + nf * 2048);
        if (moreS) STG6(gA2, gB2, aN2, bN2);
        __builtin_amdgcn_s_setprio(1);
#pragma unroll
        for (int mf = 0; mf < 4; ++mf)
#pragma unroll
            for (int nf = 0; nf < 4; ++nf)
                acc[mf][nf] = MFMA(a0[mf], b0v[nf], acc[mf][nf]);
        __builtin_amdgcn_s_setprio(0);

        // ---- P1: MFMA ks1 (16)
        __builtin_amdgcn_s_setprio(1);
#pragma unroll
        for (int mf = 0; mf < 4; ++mf)
#pragma unroll
            for (int nf = 0; nf < 4; ++nf)
                acc[mf][nf] = MFMA(a1[mf], b1v[nf], acc[mf][nf]);
        __builtin_amdgcn_s_setprio(0);

        // ---- boundary: t+1's loads landed (vmcnt leaves t+2's 6), all waves synced
        if (moreT) {
            if (moreS) { WAITVM(6); } else { WAITVM(0); }
            BAR();
#pragma unroll
            for (int mf = 0; mf < 4; ++mf) a0[mf] = *(const bf16x8*)(rdA0 + aN1 + mf * 2048);
#pragma unroll
            for (int nf = 0; nf < 4; ++nf) b0v[nf] = *(const bf16x8*)(rdB0 + bN1 + nf * 2048);
        }

        // ---- expert boundary: fold acc into gate-weighted out accumulator
        if ((t & 15) == 15) {
            const int e = t >> 4;
            float sc[4], tc[4];
#pragma unroll
            for (int nf = 0; nf < 4; ++nf) {
                sc[nf] = Sv[e * H2_ + cbase + nf * 16];
                tc[nf] = Tv[e * H2_ + cbase + nf * 16];
            }
#pragma unroll
            for (int mf = 0; mf < 4; ++mf) {
#pragma unroll
                for (int r = 0; r < 4; ++r) {
                    const int row = rbase + mf * 16 + r;
                    const float g = gate[(size_t)row * E_ + e];
#pragma unroll
                    for (int nf = 0; nf < 4; ++nf) {
                        float x = acc[mf][nf][r] * sc[nf] + tc[nf];
                        x = x > 0.f ? x : 0.f;
                        oacc[mf][nf][r] += g * x;
                    }
                }
            }
#pragma unroll
            for (int mf = 0; mf < 4; ++mf)
#pragma unroll
                for (int nf = 0; nf < 4; ++nf)
                    acc[mf][nf] = (f32x4){0.f, 0.f, 0.f, 0.f};
        }

        const int ta = aCur; aCur = aN1; aN1 = aN2; aN2 = ta;
        const int tb = bCur; bCur = bN1; bN1 = bN2; bN2 = tb;
    }

#pragma unroll
    for (int mf = 0; mf < 4; ++mf) {
#pragma unroll
        for (int r = 0; r < 4; ++r) {
            const int row = rbase + mf * 16 + r;
#pragma unroll
            for (int nf = 0; nf < 4; ++nf)
                outp[(size_t)row * H2_ + cbase + nf * 16] = oacc[mf][nf][r];
        }
    }
#undef STG6
}

// ---------------- launch ----------------

extern "C" void kernel_launch(void* const* d_in, const int* in_sizes, int n_in,
                              void* d_out, int out_size, void* d_ws, size_t ws_size,
                              hipStream_t stream) {
    (void)in_sizes; (void)n_in; (void)out_size; (void)ws_size;

    const float* input    = (const float*)d_in[0];
    const float* sideinfo = (const float*)d_in[1];
    const float* W1   = (const float*)d_in[2];
    const float* b1   = (const float*)d_in[3];
    const float* g1   = (const float*)d_in[4];
    const float* be1  = (const float*)d_in[5];
    const float* m1   = (const float*)d_in[6];
    const float* v1   = (const float*)d_in[7];
    const float* W2   = (const float*)d_in[8];
    const float* b2   = (const float*)d_in[9];
    const float* g2   = (const float*)d_in[10];
    const float* be2  = (const float*)d_in[11];
    const float* m2   = (const float*)d_in[12];
    const float* v2   = (const float*)d_in[13];
    const float* Wg   = (const float*)d_in[14];
    const float* bg   = (const float*)d_in[15];

    char* w = (char*)d_ws;
    size_t off = 0;
    auto carve = [&](size_t bytes) {
        void* p = w + off;
        off += (bytes + 255) & ~(size_t)255;
        return p;
    };
    ushort* Abf  = (ushort*)carve((size_t)B_ * D_ * 2);
    ushort* W1T  = (ushort*)carve((size_t)E_ * H1_ * D_ * 2);
    ushort* W2T  = (ushort*)carve((size_t)E_ * H2_ * H1_ * 2);
    ushort* hbuf = (ushort*)carve((size_t)E_ * B_ * H1_ * 2);
    float*  S1   = (float*)carve((size_t)E_ * H1_ * 4);
    float*  T1   = (float*)carve((size_t)E_ * H1_ * 4);
    float*  S2   = (float*)carve((size_t)E_ * H2_ * 4);
    float*  T2   = (float*)carve((size_t)E_ * H2_ * 4);
    float*  gatep = (float*)carve((size_t)B_ * E_ * 4);

    float* outp = (float*)d_out;

    hipFuncSetAttribute(reinterpret_cast<const void*>(&gemm8<1>),
                        hipFuncAttributeMaxDynamicSharedMemorySize, 163840);
    hipFuncSetAttribute(reinterpret_cast<const void*>(&gemm2e),
                        hipFuncAttributeMaxDynamicSharedMemorySize, 147456);

    cvt_bf16_kernel<<<4096, 256, 0, stream>>>(input, Abf, (long)B_ * D_);
    transpose_cvt_kernel<<<E_ * (D_ / 64) * (H1_ / 64), 256, 0, stream>>>(W1, W1T, D_, H1_);
    transpose_cvt_kernel<<<E_ * (H1_ / 64) * (H2_ / 64), 256, 0, stream>>>(W2, W2T, H1_, H2_);
    fold_bn_kernel<<<(E_ * H1_ + 255) / 256, 256, 0, stream>>>(g1, be1, m1, v1, b1, S1, T1, E_ * H1_);
    fold_bn_kernel<<<(E_ * H2_ + 255) / 256, 256, 0, stream>>>(g2, be2, m2, v2, b2, S2, T2, E_ * H2_);
    gate_kernel<<<B_ / 4, 256, 0, stream>>>(sideinfo, Wg, bg, gatep);

    // GEMM1: [B,D] x [D,H1] per expert -> h bf16 [E][B][H1]
    gemm8<1><<<E_ * (B_ / 256) * (H1_ / 256), 512, 163840, stream>>>(
        Abf, W1T, 0L, S1, T1, hbuf, nullptr, nullptr, B_, H1_, D_, H1_ / 256, B_ / 256);

    // GEMM2e: expert-loop, gate-weighted, writes out exactly once (no atomics)
    gemm2e<<<(B_ / 128) * (H2_ / 256), 512, 147456, stream>>>(
        hbuf, W2T, S2, T2, gatep, outp);
}

// Round 12
// 708.040 us; speedup vs baseline: 1.0999x; 1.0999x over previous
//
#include <hip/hip_runtime.h>
#include <hip/hip_bf16.h>

// Problem constants
static constexpr int B_  = 16384;
static constexpr int D_  = 2048;
static constexpr int S_  = 512;
static constexpr int E_  = 8;
static constexpr int H1_ = 1024;
static constexpr int H2_ = 512;
static constexpr float EPS_ = 1e-5f;

typedef __bf16 bf16x8 __attribute__((ext_vector_type(8)));
typedef float  f32x4  __attribute__((ext_vector_type(4)));

static __device__ __forceinline__ unsigned short f2bf(float f) {
    unsigned u = __float_as_uint(f);
    unsigned r = (u + 0x7fffu + ((u >> 16) & 1u)) >> 16;   // RTNE
    return (unsigned short)r;
}

// ---------------- prepass kernels (verified R1/R2) ----------------

__global__ void cvt_bf16_kernel(const float* __restrict__ in, ushort* __restrict__ out, long n) {
    long i = ((long)blockIdx.x * blockDim.x + threadIdx.x) * 4;
    long stride = (long)gridDim.x * blockDim.x * 4;
    for (; i < n; i += stride) {
        float4 v = *(const float4*)(in + i);
        ushort4 o;
        o.x = f2bf(v.x); o.y = f2bf(v.y); o.z = f2bf(v.z); o.w = f2bf(v.w);
        *(ushort4*)(out + i) = o;
    }
}

// in: [E][R][C] f32  ->  out: [E][C][R] bf16
__global__ void transpose_cvt_kernel(const float* __restrict__ in, ushort* __restrict__ out,
                                     int R, int C) {
    __shared__ float t[64][65];
    int nbr = R >> 6, nbc = C >> 6;
    int bid = blockIdx.x;
    int e = bid / (nbr * nbc);
    int rem = bid % (nbr * nbc);
    int br = (rem / nbc) << 6, bc = (rem % nbc) << 6;
    const float* ip = in + (size_t)e * R * C;
    ushort* op = out + (size_t)e * R * C;
    int tcol = (threadIdx.x & 15) * 4;
    int trow = threadIdx.x >> 4;
#pragma unroll
    for (int p = 0; p < 4; p++) {
        int r = trow + p * 16;
        float4 v = *(const float4*)(ip + (size_t)(br + r) * C + bc + tcol);
        t[r][tcol + 0] = v.x; t[r][tcol + 1] = v.y; t[r][tcol + 2] = v.z; t[r][tcol + 3] = v.w;
    }
    __syncthreads();
#pragma unroll
    for (int p = 0; p < 4; p++) {
        int c = trow + p * 16;
        ushort4 o;
        o.x = f2bf(t[tcol + 0][c]);
        o.y = f2bf(t[tcol + 1][c]);
        o.z = f2bf(t[tcol + 2][c]);
        o.w = f2bf(t[tcol + 3][c]);
        *(ushort4*)(op + (size_t)(bc + c) * R + br + tcol) = o;
    }
}

__global__ void fold_bn_kernel(const float* __restrict__ gamma, const float* __restrict__ beta,
                               const float* __restrict__ mean, const float* __restrict__ var,
                               const float* __restrict__ bias,
                               float* __restrict__ Sv, float* __restrict__ Tv, int n) {
    int i = blockIdx.x * 256 + threadIdx.x;
    if (i < n) {
        float s = gamma[i] * rsqrtf(var[i] + EPS_);
        Sv[i] = s;
        Tv[i] = (bias[i] - mean[i]) * s + beta[i];
    }
}

__global__ void gate_kernel(const float* __restrict__ side, const float* __restrict__ Wg,
                            const float* __restrict__ bg, float* __restrict__ gate) {
    int wid = threadIdx.x >> 6, lane = threadIdx.x & 63;
    int b = blockIdx.x * 4 + wid;
    const float* sp = side + (size_t)b * S_ + lane * 8;
    float4 v0 = *(const float4*)sp;
    float4 v1 = *(const float4*)(sp + 4);
    float sv[8] = {v0.x, v0.y, v0.z, v0.w, v1.x, v1.y, v1.z, v1.w};
    float acc[E_] = {0,0,0,0,0,0,0,0};
    const float* wrow = Wg + (size_t)(lane * 8) * E_;
#pragma unroll
    for (int j = 0; j < 8; j++) {
        float4 w0 = *(const float4*)(wrow + j * E_);
        float4 w1 = *(const float4*)(wrow + j * E_ + 4);
        acc[0] += sv[j] * w0.x; acc[1] += sv[j] * w0.y;
        acc[2] += sv[j] * w0.z; acc[3] += sv[j] * w0.w;
        acc[4] += sv[j] * w1.x; acc[5] += sv[j] * w1.y;
        acc[6] += sv[j] * w1.z; acc[7] += sv[j] * w1.w;
    }
#pragma unroll
    for (int off = 32; off; off >>= 1)
#pragma unroll
        for (int e = 0; e < E_; e++) acc[e] += __shfl_xor(acc[e], off, 64);
    float m = -1e30f;
#pragma unroll
    for (int e = 0; e < E_; e++) { acc[e] += bg[e]; m = fmaxf(m, acc[e]); }
    float s = 0.f;
#pragma unroll
    for (int e = 0; e < E_; e++) { acc[e] = __expf(acc[e] - m); s += acc[e]; }
    float inv = 1.f / s;
    if (lane < E_) gate[(size_t)b * E_ + lane] = acc[lane] * inv;
}

// ---------------- shared GEMM helpers ----------------

__device__ __forceinline__ void g2lds16(const void* g, void* l) {
    __builtin_amdgcn_global_load_lds((const __attribute__((address_space(1))) unsigned int*)g,
                                     (__attribute__((address_space(3))) unsigned int*)l,
                                     16, 0, 0);
}

#define BAR()      asm volatile("s_barrier" ::: "memory")
#define WAITVM(n)  asm volatile("s_waitcnt vmcnt(" #n ")" ::: "memory")
#define MFMA(a,b,c) __builtin_amdgcn_mfma_f32_16x16x32_bf16((a),(b),(c),0,0,0)

// ---------------- GEMM1: 256x256, counted-vmcnt (T4) asymmetric pipeline ----------------
// (verified R10: 490us, MfmaUtil 52%, 0 bank conflicts) — EXACT REVERT from R11's
// 32x32 variant (which hit a structural 4-way LDS bank conflict: 32 rows x 16B
// reads from a 128B-pitch row have only 8 column slots -> >=4 lanes/bank).
// LDS map (160 KiB): B bufs at {0,32768,65536} (triple, rotating);
//                    A bufs at {98304,131072} (double, bi = t&1).
// Swizzle: LDS[row][x] = global[row][x ^ ((row&7)<<4)] (both-sides, rule #21).
// Schedule: tile t reads A buf bi / B buf bCur(t%3);
//   P0 stages A(t+1)->bi^1, P1/P2 stage B(t+2)->bN2; boundary vmcnt(4)+BAR
//   (A(t+1) retired, B(t+2)'s 4 in flight); vmcnt(0) only at t==NT-2.

template<int EPI>
__global__ __launch_bounds__(512, 2)
void gemm8(const ushort* __restrict__ A, const ushort* __restrict__ Bt, long aBatch,
           const float* __restrict__ Sv, const float* __restrict__ Tv,
           ushort* __restrict__ hout, float* __restrict__ outp, const float* __restrict__ gate,
           int M, int N, int K, int tilesN, int tilesM)
{
    extern __shared__ char smem[];

    const int NT  = K >> 6;
    const int tpe = tilesM * tilesN;

    const int nwg = gridDim.x, per = nwg >> 3;
    const int b0  = blockIdx.x;
    const int bid = (b0 & 7) * per + (b0 >> 3);

    const int e   = bid / tpe;
    const int rem = bid % tpe;
    const int tm  = rem / tilesN, tn = rem % tilesN;

    const char* aBase = (const char*)(A + (size_t)e * aBatch + (size_t)tm * 256 * K);
    const char* bBase = (const char*)(Bt + (size_t)e * N * K + (size_t)tn * 256 * K);
    const size_t rowB = (size_t)K * 2;
    const size_t half2 = 64 * rowB;
    const size_t half1 = 128 * rowB;

    const int tid = threadIdx.x, w = tid >> 6, lane = tid & 63;
    const int wm = w >> 2, wn = w & 3;

    const int srow = tid >> 3;
    const int scol_sw = ((tid & 7) * 16) ^ ((srow & 7) << 4);
    const int ldsW = w * 1024;

    const int lr = lane & 15;
    const int cks0 = ((lane >> 4) * 16) ^ ((lane & 7) << 4);
    const int cks1 = (64 + (lane >> 4) * 16) ^ ((lane & 7) << 4);
    // A region base (98304) baked into rdA*; per-tile offset = bi*32768 ONLY (R3 lesson).
    const char* rdA0 = smem + 98304 + (wm * 128 + lr) * 128 + cks0;   // A ks0
    const char* rdA1 = smem + 98304 + (wm * 128 + lr) * 128 + cks1;   // A ks1
    // B region base 0; per-tile offset = rotating bCur in {0,32768,65536}.
    const char* rdB0 = smem + (wn * 64 + lr) * 128 + cks0;            // B ks0
    const char* rdB1 = smem + (wn * 64 + lr) * 128 + cks1;            // B ks1

#define STG(gp, ldsoff) do { \
        g2lds16((gp), smem + (ldsoff)); \
        g2lds16((gp) + half2, smem + (ldsoff) + 8192); } while (0)

    const char* ga = aBase + (size_t)srow * rowB + scol_sw;
    const char* gb = bBase + (size_t)srow * rowB + scol_sw;

    f32x4 acc[8][4] = {};
    bf16x8 aC[4], aN[4], bC[4], bN[4];

    // rotating B buffer offsets: bCur = t%3, bN1 = (t+1)%3, bN2 = (t+2)%3
    int bCur = 0, bN1 = 32768, bN2 = 65536;

    // prologue: A(0)->A0, B(0)->B0, B(1)->B1; wait A(0),B(0) (4 newest = B(1))
    STG(ga,                98304 + 0 + 0     + ldsW);
    STG(ga + half1,        98304 + 0 + 16384 + ldsW);
    STG(gb,                0     + 0     + ldsW);
    STG(gb + half1,        0     + 16384 + ldsW);
    STG(gb + 128,          32768 + 0     + ldsW);
    STG(gb + half1 + 128,  32768 + 16384 + ldsW);
    WAITVM(4);
    BAR();

#pragma unroll
    for (int mf = 0; mf < 4; ++mf) aC[mf] = *(const bf16x8*)(rdA0 + mf * 2048);
#pragma unroll
    for (int nf = 0; nf < 4; ++nf) bC[nf] = *(const bf16x8*)(rdB0 + nf * 2048);

    // staging pointers: A -> tile t+1; B -> tile t+2 (advance 128 B/tile)
    const char* spA0 = ga + 128;
    const char* spA1 = ga + half1 + 128;
    const char* spB0 = gb + 256;
    const char* spB1 = gb + half1 + 256;

#pragma unroll 2
    for (int t = 0; t < NT; ++t) {
        const int bi    = t & 1;
        const int oRA   = bi * 32768;              // A read offset
        const int oRAN  = (bi ^ 1) * 32768;        // next-tile A read offset
        const int oSA   = 98304 + (bi ^ 1) * 32768; // A stage base (region + buf)
        const bool moreA = (t < NT - 1);
        const bool moreB = (t < NT - 2);

        // ---- P0: prefetch A ks0 hi; stage A(t+1) (4 loads, FIRST); MFMA aC(ks0,lo) x bC
#pragma unroll
        for (int mf = 0; mf < 4; ++mf) aN[mf] = *(const bf16x8*)(rdA0 + oRA + (4 + mf) * 2048);
        if (moreA) {
            STG(spA0, oSA + 0 + ldsW);
            STG(spA1, oSA + 16384 + ldsW);
        }
        __builtin_amdgcn_s_setprio(1);
#pragma unroll
        for (int mf = 0; mf < 4; ++mf)
#pragma unroll
            for (int nf = 0; nf < 4; ++nf)
                acc[mf][nf] = MFMA(aC[mf], bC[nf], acc[mf][nf]);
        __builtin_amdgcn_s_setprio(0);

        // ---- P1: prefetch A ks1 lo + B ks1; stage B(t+2) lo; MFMA aN(ks0,hi) x bC
#pragma unroll
        for (int mf = 0; mf < 4; ++mf) aC[mf] = *(const bf16x8*)(rdA1 + oRA + mf * 2048);
#pragma unroll
        for (int nf = 0; nf < 4; ++nf) bN[nf] = *(const bf16x8*)(rdB1 + bCur + nf * 2048);
        if (moreB) STG(spB0, bN2 + 0 + ldsW);
        __builtin_amdgcn_s_setprio(1);
#pragma unroll
        for (int mf = 0; mf < 4; ++mf)
#pragma unroll
            for (int nf = 0; nf < 4; ++nf)
                acc[4 + mf][nf] = MFMA(aN[mf], bC[nf], acc[4 + mf][nf]);
        __builtin_amdgcn_s_setprio(0);

        // ---- P2: prefetch A ks1 hi; stage B(t+2) hi; MFMA aC(ks1,lo) x bN
#pragma unroll
        for (int mf = 0; mf < 4; ++mf) aN[mf] = *(const bf16x8*)(rdA1 + oRA + (4 + mf) * 2048);
        if (moreB) STG(spB1, bN2 + 16384 + ldsW);
        __builtin_amdgcn_s_setprio(1);
#pragma unroll
        for (int mf = 0; mf < 4; ++mf)
#pragma unroll
            for (int nf = 0; nf < 4; ++nf)
                acc[mf][nf] = MFMA(aC[mf], bN[nf], acc[mf][nf]);
        __builtin_amdgcn_s_setprio(0);

        // ---- P3: MFMA aN(ks1,hi) x bN
        __builtin_amdgcn_s_setprio(1);
#pragma unroll
        for (int mf = 0; mf < 4; ++mf)
#pragma unroll
            for (int nf = 0; nf < 4; ++nf)
                acc[4 + mf][nf] = MFMA(aN[mf], bN[nf], acc[4 + mf][nf]);
        __builtin_amdgcn_s_setprio(0);

        // ---- boundary: counted vmcnt — A(t+1) retired, B(t+2)'s 4 stay in flight
        if (moreA) {
            if (moreB) { WAITVM(4); } else { WAITVM(0); }
            BAR();
#pragma unroll
            for (int mf = 0; mf < 4; ++mf) aC[mf] = *(const bf16x8*)(rdA0 + oRAN + mf * 2048);
#pragma unroll
            for (int nf = 0; nf < 4; ++nf) bC[nf] = *(const bf16x8*)(rdB0 + bN1 + nf * 2048);
        }

        spA0 += 128; spA1 += 128; spB0 += 128; spB1 += 128;
        const int tb = bCur; bCur = bN1; bN1 = bN2; bN2 = tb;
    }

    // epilogue: C/D layout col = lane&15, row = (lane>>4)*4 + reg
    const int rbase = tm * 256 + wm * 128 + (lane >> 4) * 4;
    const int cbase = tn * 256 + wn * 64 + lr;
    if (EPI == 1) {
#pragma unroll
        for (int nf = 0; nf < 4; ++nf) {
            const int col = cbase + nf * 16;
            const float s = Sv[e * N + col];
            const float tt = Tv[e * N + col];
#pragma unroll
            for (int mf = 0; mf < 8; ++mf) {
                const int row0 = rbase + mf * 16;
                f32x4 v = acc[mf][nf];
#pragma unroll
                for (int r = 0; r < 4; ++r) {
                    float x = v[r] * s + tt;
                    x = x > 0.f ? x : 0.f;
                    hout[((size_t)e * M + row0 + r) * N + col] = f2bf(x);
                }
            }
        }
    }
#undef STG
}

// ---------------- GEMM2e: expert-loop, TRIPLE-buffered counted-vmcnt pipeline ----------------
// (verified R9/R10) out[b][n] = sum_e gate[b][e] * relu(bn2_e( h[e][b] @ W2T[e][n] ))
// BM=128, BN=256; grid = 256 blocks = 1/CU. Flat tau over (e,kt), NT=128.
// LDS 144 KiB: B bufs {0,32768,65536}; A bufs {98304,114688,131072}.

__global__ __launch_bounds__(512, 2)
void gemm2e(const ushort* __restrict__ H, const ushort* __restrict__ W2T,
            const float* __restrict__ Sv, const float* __restrict__ Tv,
            const float* __restrict__ gate, float* __restrict__ outp)
{
    extern __shared__ char smem[];

    const int b0 = blockIdx.x;
    const int bid = (b0 & 7) * 32 + (b0 >> 3);
    const int tm = bid >> 1, tn = bid & 1;

    const size_t rowB  = (size_t)H1_ * 2;
    const size_t strAE = (size_t)B_ * H1_ * 2;
    const size_t strBE = (size_t)H2_ * H1_ * 2;
    const size_t half2 = 64 * rowB;
    const size_t halfB = 128 * rowB;

    const int tid = threadIdx.x, w = tid >> 6, lane = tid & 63;
    const int wm = w >> 2, wn = w & 3;

    const int srow = tid >> 3;
    const int scol_sw = ((tid & 7) * 16) ^ ((srow & 7) << 4);
    const int ldsW = w * 1024;

    const int lr = lane & 15;
    const int cks0 = ((lane >> 4) * 16) ^ ((lane & 7) << 4);
    const int cks1 = (64 + (lane >> 4) * 16) ^ ((lane & 7) << 4);
    const char* rdA0 = smem + (wm * 64 + lr) * 128 + cks0;
    const char* rdA1 = smem + (wm * 64 + lr) * 128 + cks1;
    const char* rdB0 = smem + (wn * 64 + lr) * 128 + cks0;
    const char* rdB1 = smem + (wn * 64 + lr) * 128 + cks1;

    const char* ga = (const char*)H + (size_t)tm * 128 * rowB + (size_t)srow * rowB + scol_sw;
    const char* gb = (const char*)W2T + (size_t)tn * 256 * rowB + (size_t)srow * rowB + scol_sw;

#define STG6(gAp, gBp, aOff, bOff) do { \
        g2lds16((gAp),                 smem + (aOff) + 0     + ldsW); \
        g2lds16((gAp) + half2,         smem + (aOff) + 8192  + ldsW); \
        g2lds16((gBp),                 smem + (bOff) + 0     + ldsW); \
        g2lds16((gBp) + half2,         smem + (bOff) + 8192  + ldsW); \
        g2lds16((gBp) + halfB,         smem + (bOff) + 16384 + ldsW); \
        g2lds16((gBp) + halfB + half2, smem + (bOff) + 24576 + ldsW); } while (0)

    f32x4 acc[4][4] = {};
    f32x4 oacc[4][4] = {};
    bf16x8 a0[4], a1[4], b0v[4], b1v[4];

    int aCur = 98304, aN1 = 114688, aN2 = 131072;
    int bCur = 0,     bN1 = 32768,  bN2 = 65536;

    STG6(ga, gb, aCur, bCur);
    STG6(ga + 128, gb + 128, aN1, bN1);
    WAITVM(6);
    BAR();

#pragma unroll
    for (int mf = 0; mf < 4; ++mf) a0[mf] = *(const bf16x8*)(rdA0 + aCur + mf * 2048);
#pragma unroll
    for (int nf = 0; nf < 4; ++nf) b0v[nf] = *(const bf16x8*)(rdB0 + bCur + nf * 2048);

    const int rbase = tm * 128 + wm * 64 + (lane >> 4) * 4;
    const int cbase = tn * 256 + wn * 64 + lr;

    for (int t = 0; t < 128; ++t) {
        const int t2 = t + 2;
        const bool moreS = (t2 < 128);
        const bool moreT = (t < 127);

        const char* gA2 = ga + (size_t)(t2 >> 4) * strAE + (t2 & 15) * 128;
        const char* gB2 = gb + (size_t)(t2 >> 4) * strBE + (t2 & 15) * 128;

        // ---- P0: prefetch ks1 frags (cur); stage (t+2) -> n2; MFMA ks0 (16)
#pragma unroll
        for (int mf = 0; mf < 4; ++mf) a1[mf] = *(const bf16x8*)(rdA1 + aCur + mf * 2048);
#pragma unroll
        for (int nf = 0; nf < 4; ++nf) b1v[nf] = *(const bf16x8*)(rdB1 + bCur + nf * 2048);
        if (moreS) STG6(gA2, gB2, aN2, bN2);
        __builtin_amdgcn_s_setprio(1);
#pragma unroll
        for (int mf = 0; mf < 4; ++mf)
#pragma unroll
            for (int nf = 0; nf < 4; ++nf)
                acc[mf][nf] = MFMA(a0[mf], b0v[nf], acc[mf][nf]);
        __builtin_amdgcn_s_setprio(0);

        // ---- P1: MFMA ks1 (16)
        __builtin_amdgcn_s_setprio(1);
#pragma unroll
        for (int mf = 0; mf < 4; ++mf)
#pragma unroll
            for (int nf = 0; nf < 4; ++nf)
                acc[mf][nf] = MFMA(a1[mf], b1v[nf], acc[mf][nf]);
        __builtin_amdgcn_s_setprio(0);

        // ---- boundary: t+1's loads landed (vmcnt leaves t+2's 6), all waves synced
        if (moreT) {
            if (moreS) { WAITVM(6); } else { WAITVM(0); }
            BAR();
#pragma unroll
            for (int mf = 0; mf < 4; ++mf) a0[mf] = *(const bf16x8*)(rdA0 + aN1 + mf * 2048);
#pragma unroll
            for (int nf = 0; nf < 4; ++nf) b0v[nf] = *(const bf16x8*)(rdB0 + bN1 + nf * 2048);
        }

        // ---- expert boundary: fold acc into gate-weighted out accumulator
        if ((t & 15) == 15) {
            const int e = t >> 4;
            float sc[4], tc[4];
#pragma unroll
            for (int nf = 0; nf < 4; ++nf) {
                sc[nf] = Sv[e * H2_ + cbase + nf * 16];
                tc[nf] = Tv[e * H2_ + cbase + nf * 16];
            }
#pragma unroll
            for (int mf = 0; mf < 4; ++mf) {
#pragma unroll
                for (int r = 0; r < 4; ++r) {
                    const int row = rbase + mf * 16 + r;
                    const float g = gate[(size_t)row * E_ + e];
#pragma unroll
                    for (int nf = 0; nf < 4; ++nf) {
                        float x = acc[mf][nf][r] * sc[nf] + tc[nf];
                        x = x > 0.f ? x : 0.f;
                        oacc[mf][nf][r] += g * x;
                    }
                }
            }
#pragma unroll
            for (int mf = 0; mf < 4; ++mf)
#pragma unroll
                for (int nf = 0; nf < 4; ++nf)
                    acc[mf][nf] = (f32x4){0.f, 0.f, 0.f, 0.f};
        }

        const int ta = aCur; aCur = aN1; aN1 = aN2; aN2 = ta;
        const int tb = bCur; bCur = bN1; bN1 = bN2; bN2 = tb;
    }

#pragma unroll
    for (int mf = 0; mf < 4; ++mf) {
#pragma unroll
        for (int r = 0; r < 4; ++r) {
            const int row = rbase + mf * 16 + r;
#pragma unroll
            for (int nf = 0; nf < 4; ++nf)
                outp[(size_t)row * H2_ + cbase + nf * 16] = oacc[mf][nf][r];
        }
    }
#undef STG6
}

// ---------------- launch ----------------

extern "C" void kernel_launch(void* const* d_in, const int* in_sizes, int n_in,
                              void* d_out, int out_size, void* d_ws, size_t ws_size,
                              hipStream_t stream) {
    (void)in_sizes; (void)n_in; (void)out_size; (void)ws_size;

    const float* input    = (const float*)d_in[0];
    const float* sideinfo = (const float*)d_in[1];
    const float* W1   = (const float*)d_in[2];
    const float* b1   = (const float*)d_in[3];
    const float* g1   = (const float*)d_in[4];
    const float* be1  = (const float*)d_in[5];
    const float* m1   = (const float*)d_in[6];
    const float* v1   = (const float*)d_in[7];
    const float* W2   = (const float*)d_in[8];
    const float* b2   = (const float*)d_in[9];
    const float* g2   = (const float*)d_in[10];
    const float* be2  = (const float*)d_in[11];
    const float* m2   = (const float*)d_in[12];
    const float* v2   = (const float*)d_in[13];
    const float* Wg   = (const float*)d_in[14];
    const float* bg   = (const float*)d_in[15];

    char* w = (char*)d_ws;
    size_t off = 0;
    auto carve = [&](size_t bytes) {
        void* p = w + off;
        off += (bytes + 255) & ~(size_t)255;
        return p;
    };
    ushort* Abf  = (ushort*)carve((size_t)B_ * D_ * 2);
    ushort* W1T  = (ushort*)carve((size_t)E_ * H1_ * D_ * 2);
    ushort* W2T  = (ushort*)carve((size_t)E_ * H2_ * H1_ * 2);
    ushort* hbuf = (ushort*)carve((size_t)E_ * B_ * H1_ * 2);
    float*  S1   = (float*)carve((size_t)E_ * H1_ * 4);
    float*  T1   = (float*)carve((size_t)E_ * H1_ * 4);
    float*  S2   = (float*)carve((size_t)E_ * H2_ * 4);
    float*  T2   = (float*)carve((size_t)E_ * H2_ * 4);
    float*  gatep = (float*)carve((size_t)B_ * E_ * 4);

    float* outp = (float*)d_out;

    hipFuncSetAttribute(reinterpret_cast<const void*>(&gemm8<1>),
                        hipFuncAttributeMaxDynamicSharedMemorySize, 163840);
    hipFuncSetAttribute(reinterpret_cast<const void*>(&gemm2e),
                        hipFuncAttributeMaxDynamicSharedMemorySize, 147456);

    cvt_bf16_kernel<<<4096, 256, 0, stream>>>(input, Abf, (long)B_ * D_);
    transpose_cvt_kernel<<<E_ * (D_ / 64) * (H1_ / 64), 256, 0, stream>>>(W1, W1T, D_, H1_);
    transpose_cvt_kernel<<<E_ * (H1_ / 64) * (H2_ / 64), 256, 0, stream>>>(W2, W2T, H1_, H2_);
    fold_bn_kernel<<<(E_ * H1_ + 255) / 256, 256, 0, stream>>>(g1, be1, m1, v1, b1, S1, T1, E_ * H1_);
    fold_bn_kernel<<<(E_ * H2_ + 255) / 256, 256, 0, stream>>>(g2, be2, m2, v2, b2, S2, T2, E_ * H2_);
    gate_kernel<<<B_ / 4, 256, 0, stream>>>(sideinfo, Wg, bg, gatep);

    // GEMM1: [B,D] x [D,H1] per expert -> h bf16 [E][B][H1]
    gemm8<1><<<E_ * (B_ / 256) * (H1_ / 256), 512, 163840, stream>>>(
        Abf, W1T, 0L, S1, T1, hbuf, nullptr, nullptr, B_, H1_, D_, H1_ / 256, B_ / 256);

    // GEMM2e: expert-loop, gate-weighted, writes out exactly once (no atomics)
    gemm2e<<<(B_ / 128) * (H2_ / 256), 512, 147456, stream>>>(
        hbuf, W2T, S2, T2, gatep, outp);
}

// Round 13
// 695.721 us; speedup vs baseline: 1.1194x; 1.0177x over previous
//
#include <hip/hip_runtime.h>
#include <hip/hip_bf16.h>

// Problem constants
static constexpr int B_  = 16384;
static constexpr int D_  = 2048;
static constexpr int S_  = 512;
static constexpr int E_  = 8;
static constexpr int H1_ = 1024;
static constexpr int H2_ = 512;
static constexpr float EPS_ = 1e-5f;

typedef __bf16 bf16x8 __attribute__((ext_vector_type(8)));
typedef float  f32x4  __attribute__((ext_vector_type(4)));

static __device__ __forceinline__ unsigned short f2bf(float f) {
    unsigned u = __float_as_uint(f);
    unsigned r = (u + 0x7fffu + ((u >> 16) & 1u)) >> 16;   // RTNE
    return (unsigned short)r;
}

// ---------------- prepass kernels (verified R1/R2) ----------------

__global__ void cvt_bf16_kernel(const float* __restrict__ in, ushort* __restrict__ out, long n) {
    long i = ((long)blockIdx.x * blockDim.x + threadIdx.x) * 4;
    long stride = (long)gridDim.x * blockDim.x * 4;
    for (; i < n; i += stride) {
        float4 v = *(const float4*)(in + i);
        ushort4 o;
        o.x = f2bf(v.x); o.y = f2bf(v.y); o.z = f2bf(v.z); o.w = f2bf(v.w);
        *(ushort4*)(out + i) = o;
    }
}

// in: [E][R][C] f32  ->  out: [E][C][R] bf16
__global__ void transpose_cvt_kernel(const float* __restrict__ in, ushort* __restrict__ out,
                                     int R, int C) {
    __shared__ float t[64][65];
    int nbr = R >> 6, nbc = C >> 6;
    int bid = blockIdx.x;
    int e = bid / (nbr * nbc);
    int rem = bid % (nbr * nbc);
    int br = (rem / nbc) << 6, bc = (rem % nbc) << 6;
    const float* ip = in + (size_t)e * R * C;
    ushort* op = out + (size_t)e * R * C;
    int tcol = (threadIdx.x & 15) * 4;
    int trow = threadIdx.x >> 4;
#pragma unroll
    for (int p = 0; p < 4; p++) {
        int r = trow + p * 16;
        float4 v = *(const float4*)(ip + (size_t)(br + r) * C + bc + tcol);
        t[r][tcol + 0] = v.x; t[r][tcol + 1] = v.y; t[r][tcol + 2] = v.z; t[r][tcol + 3] = v.w;
    }
    __syncthreads();
#pragma unroll
    for (int p = 0; p < 4; p++) {
        int c = trow + p * 16;
        ushort4 o;
        o.x = f2bf(t[tcol + 0][c]);
        o.y = f2bf(t[tcol + 1][c]);
        o.z = f2bf(t[tcol + 2][c]);
        o.w = f2bf(t[tcol + 3][c]);
        *(ushort4*)(op + (size_t)(bc + c) * R + br + tcol) = o;
    }
}

__global__ void fold_bn_kernel(const float* __restrict__ gamma, const float* __restrict__ beta,
                               const float* __restrict__ mean, const float* __restrict__ var,
                               const float* __restrict__ bias,
                               float* __restrict__ Sv, float* __restrict__ Tv, int n) {
    int i = blockIdx.x * 256 + threadIdx.x;
    if (i < n) {
        float s = gamma[i] * rsqrtf(var[i] + EPS_);
        Sv[i] = s;
        Tv[i] = (bias[i] - mean[i]) * s + beta[i];
    }
}

__global__ void gate_kernel(const float* __restrict__ side, const float* __restrict__ Wg,
                            const float* __restrict__ bg, float* __restrict__ gate) {
    int wid = threadIdx.x >> 6, lane = threadIdx.x & 63;
    int b = blockIdx.x * 4 + wid;
    const float* sp = side + (size_t)b * S_ + lane * 8;
    float4 v0 = *(const float4*)sp;
    float4 v1 = *(const float4*)(sp + 4);
    float sv[8] = {v0.x, v0.y, v0.z, v0.w, v1.x, v1.y, v1.z, v1.w};
    float acc[E_] = {0,0,0,0,0,0,0,0};
    const float* wrow = Wg + (size_t)(lane * 8) * E_;
#pragma unroll
    for (int j = 0; j < 8; j++) {
        float4 w0 = *(const float4*)(wrow + j * E_);
        float4 w1 = *(const float4*)(wrow + j * E_ + 4);
        acc[0] += sv[j] * w0.x; acc[1] += sv[j] * w0.y;
        acc[2] += sv[j] * w0.z; acc[3] += sv[j] * w0.w;
        acc[4] += sv[j] * w1.x; acc[5] += sv[j] * w1.y;
        acc[6] += sv[j] * w1.z; acc[7] += sv[j] * w1.w;
    }
#pragma unroll
    for (int off = 32; off; off >>= 1)
#pragma unroll
        for (int e = 0; e < E_; e++) acc[e] += __shfl_xor(acc[e], off, 64);
    float m = -1e30f;
#pragma unroll
    for (int e = 0; e < E_; e++) { acc[e] += bg[e]; m = fmaxf(m, acc[e]); }
    float s = 0.f;
#pragma unroll
    for (int e = 0; e < E_; e++) { acc[e] = __expf(acc[e] - m); s += acc[e]; }
    float inv = 1.f / s;
    if (lane < E_) gate[(size_t)b * E_ + lane] = acc[lane] * inv;
}

// ---------------- shared GEMM helpers ----------------

__device__ __forceinline__ void g2lds16(const void* g, void* l) {
    __builtin_amdgcn_global_load_lds((const __attribute__((address_space(1))) unsigned int*)g,
                                     (__attribute__((address_space(3))) unsigned int*)l,
                                     16, 0, 0);
}

#define BAR()      asm volatile("s_barrier" ::: "memory")
#define WAITVM(n)  asm volatile("s_waitcnt vmcnt(" #n ")" ::: "memory")
#define MFMA(a,b,c) __builtin_amdgcn_mfma_f32_16x16x32_bf16((a),(b),(c),0,0,0)

// ---------------- GEMM1: 256x256, 16-wave TLP variant (R13) ----------------
// Mechanism change vs R12: 1024 threads = 16 waves = 4 waves/SIMD. Just-in-time
// fragment reads (no ping-pong) shrink regs to ~115 (<=128 via launch_bounds)
// so 4 waves/SIMD fit; TLP overlaps one wave's lgkm-wait with others' MFMA
// (m114 mechanism) instead of relying on intra-wave schedule finesse.
// LDS map unchanged (160 KiB): B bufs {0,32768,65536} triple; A bufs
// {98304,131072} double. Swizzle unchanged: LDS[row][x]=g[row][x^((row&7)<<4)].
// Staging: 1024 threads cover a 128-row half per ONE g2lds. 4 loads/thread/tile:
//   P0 stages A(t+1) lo+hi -> bi^1; P1 stages B(t+2) lo+hi -> bN2.
// Boundary: vmcnt(2) (A(t+1)'s 2 retired, B(t+2)'s 2 in flight) + BAR;
// vmcnt(0) only at t==NT-2. Race audit = R10 proof shape (disjoint bufs).

template<int EPI>
__global__ __launch_bounds__(1024, 4)
void gemm8(const ushort* __restrict__ A, const ushort* __restrict__ Bt, long aBatch,
           const float* __restrict__ Sv, const float* __restrict__ Tv,
           ushort* __restrict__ hout, float* __restrict__ outp, const float* __restrict__ gate,
           int M, int N, int K, int tilesN, int tilesM)
{
    extern __shared__ char smem[];

    const int NT  = K >> 6;
    const int tpe = tilesM * tilesN;

    const int nwg = gridDim.x, per = nwg >> 3;
    const int b0  = blockIdx.x;
    const int bid = (b0 & 7) * per + (b0 >> 3);

    const int e   = bid / tpe;
    const int rem = bid % tpe;
    const int tm  = rem / tilesN, tn = rem % tilesN;

    const char* aBase = (const char*)(A + (size_t)e * aBatch + (size_t)tm * 256 * K);
    const char* bBase = (const char*)(Bt + (size_t)e * N * K + (size_t)tn * 256 * K);
    const size_t rowB = (size_t)K * 2;
    const size_t half1 = 128 * rowB;     // hi-half global row offset

    const int tid = threadIdx.x, w = tid >> 6, lane = tid & 63;
    const int wm = w >> 2, wn = w & 3;   // 4M x 4N wave grid; wave tile 64x64

    const int srow = tid >> 3;                                   // 0..127
    const int scol_sw = ((tid & 7) * 16) ^ ((srow & 7) << 4);
    const int ldsW = w * 1024;                                   // wave-uniform stage base

    const int lr = lane & 15;
    const int cks0 = ((lane >> 4) * 16) ^ ((lane & 7) << 4);
    const int cks1 = (64 + (lane >> 4) * 16) ^ ((lane & 7) << 4);
    // A region base (98304) baked in; per-tile offset = bi*32768 ONLY (R3 lesson).
    const char* rdA0 = smem + 98304 + (wm * 64 + lr) * 128 + cks0;
    const char* rdA1 = smem + 98304 + (wm * 64 + lr) * 128 + cks1;
    const char* rdB0 = smem + (wn * 64 + lr) * 128 + cks0;
    const char* rdB1 = smem + (wn * 64 + lr) * 128 + cks1;

    // stage a full 256-row operand tile = 2 g2lds (lo rows 0-127, hi 128-255)
#define STG2T(gp, ldsoff) do { \
        g2lds16((gp), smem + (ldsoff) + ldsW); \
        g2lds16((gp) + half1, smem + (ldsoff) + 16384 + ldsW); } while (0)

    const char* ga = aBase + (size_t)srow * rowB + scol_sw;
    const char* gb = bBase + (size_t)srow * rowB + scol_sw;

    f32x4 acc[4][4] = {};
    bf16x8 a[4], b[4];

    // rotating B buffer offsets: bCur = t%3, bN1 = (t+1)%3, bN2 = (t+2)%3
    int bCur = 0, bN1 = 32768, bN2 = 65536;

    // prologue: A(0)->A0, B(0)->B0, B(1)->B1; vmcnt(2) retires A(0),B(0)
    STG2T(ga,       98304);
    STG2T(gb,       0);
    STG2T(gb + 128, 32768);
    WAITVM(2);
    BAR();

    // staging pointers: A -> tile t+1; B -> tile t+2 (advance 128 B/tile)
    const char* spA = ga + 128;
    const char* spB = gb + 256;

    for (int t = 0; t < NT; ++t) {
        const int bi    = t & 1;
        const int oRA   = bi * 32768;               // A read offset
        const int oSA   = 98304 + (bi ^ 1) * 32768; // A stage base
        const bool moreA = (t < NT - 1);
        const bool moreB = (t < NT - 2);

        // ---- P0: read frags ks0 (JIT); stage A(t+1); MFMA ks0 (16)
#pragma unroll
        for (int mf = 0; mf < 4; ++mf) a[mf] = *(const bf16x8*)(rdA0 + oRA + mf * 2048);
#pragma unroll
        for (int nf = 0; nf < 4; ++nf) b[nf] = *(const bf16x8*)(rdB0 + bCur + nf * 2048);
        if (moreA) STG2T(spA, oSA);
        __builtin_amdgcn_s_setprio(1);
#pragma unroll
        for (int mf = 0; mf < 4; ++mf)
#pragma unroll
            for (int nf = 0; nf < 4; ++nf)
                acc[mf][nf] = MFMA(a[mf], b[nf], acc[mf][nf]);
        __builtin_amdgcn_s_setprio(0);

        // ---- P1: read frags ks1 (JIT); stage B(t+2); MFMA ks1 (16)
#pragma unroll
        for (int mf = 0; mf < 4; ++mf) a[mf] = *(const bf16x8*)(rdA1 + oRA + mf * 2048);
#pragma unroll
        for (int nf = 0; nf < 4; ++nf) b[nf] = *(const bf16x8*)(rdB1 + bCur + nf * 2048);
        if (moreB) STG2T(spB, bN2);
        __builtin_amdgcn_s_setprio(1);
#pragma unroll
        for (int mf = 0; mf < 4; ++mf)
#pragma unroll
            for (int nf = 0; nf < 4; ++nf)
                acc[mf][nf] = MFMA(a[mf], b[nf], acc[mf][nf]);
        __builtin_amdgcn_s_setprio(0);

        // ---- boundary: counted vmcnt — A(t+1) retired, B(t+2)'s 2 stay in flight
        if (moreA) {
            if (moreB) { WAITVM(2); } else { WAITVM(0); }
            BAR();
        }

        spA += 128; spB += 128;
        const int tb = bCur; bCur = bN1; bN1 = bN2; bN2 = tb;
    }

    // epilogue: C/D layout col = lane&15, row = (lane>>4)*4 + reg
    const int rbase = tm * 256 + wm * 64 + (lane >> 4) * 4;
    const int cbase = tn * 256 + wn * 64 + lr;
    if (EPI == 1) {
#pragma unroll
        for (int nf = 0; nf < 4; ++nf) {
            const int col = cbase + nf * 16;
            const float s = Sv[e * N + col];
            const float tt = Tv[e * N + col];
#pragma unroll
            for (int mf = 0; mf < 4; ++mf) {
                const int row0 = rbase + mf * 16;
                f32x4 v = acc[mf][nf];
#pragma unroll
                for (int r = 0; r < 4; ++r) {
                    float x = v[r] * s + tt;
                    x = x > 0.f ? x : 0.f;
                    hout[((size_t)e * M + row0 + r) * N + col] = f2bf(x);
                }
            }
        }
    }
#undef STG2T
}

// ---------------- GEMM2e: expert-loop, TRIPLE-buffered counted-vmcnt pipeline ----------------
// (verified R9/R10/R12 — UNCHANGED) out[b][n] = sum_e gate[b][e]*relu(bn2_e(h@W2T))
// BM=128, BN=256; grid = 256 blocks = 1/CU. Flat tau over (e,kt), NT=128.
// LDS 144 KiB: B bufs {0,32768,65536}; A bufs {98304,114688,131072}.

__global__ __launch_bounds__(512, 2)
void gemm2e(const ushort* __restrict__ H, const ushort* __restrict__ W2T,
            const float* __restrict__ Sv, const float* __restrict__ Tv,
            const float* __restrict__ gate, float* __restrict__ outp)
{
    extern __shared__ char smem[];

    const int b0 = blockIdx.x;
    const int bid = (b0 & 7) * 32 + (b0 >> 3);
    const int tm = bid >> 1, tn = bid & 1;

    const size_t rowB  = (size_t)H1_ * 2;
    const size_t strAE = (size_t)B_ * H1_ * 2;
    const size_t strBE = (size_t)H2_ * H1_ * 2;
    const size_t half2 = 64 * rowB;
    const size_t halfB = 128 * rowB;

    const int tid = threadIdx.x, w = tid >> 6, lane = tid & 63;
    const int wm = w >> 2, wn = w & 3;

    const int srow = tid >> 3;
    const int scol_sw = ((tid & 7) * 16) ^ ((srow & 7) << 4);
    const int ldsW = w * 1024;

    const int lr = lane & 15;
    const int cks0 = ((lane >> 4) * 16) ^ ((lane & 7) << 4);
    const int cks1 = (64 + (lane >> 4) * 16) ^ ((lane & 7) << 4);
    const char* rdA0 = smem + (wm * 64 + lr) * 128 + cks0;
    const char* rdA1 = smem + (wm * 64 + lr) * 128 + cks1;
    const char* rdB0 = smem + (wn * 64 + lr) * 128 + cks0;
    const char* rdB1 = smem + (wn * 64 + lr) * 128 + cks1;

    const char* ga = (const char*)H + (size_t)tm * 128 * rowB + (size_t)srow * rowB + scol_sw;
    const char* gb = (const char*)W2T + (size_t)tn * 256 * rowB + (size_t)srow * rowB + scol_sw;

#define STG6(gAp, gBp, aOff, bOff) do { \
        g2lds16((gAp),                 smem + (aOff) + 0     + ldsW); \
        g2lds16((gAp) + half2,         smem + (aOff) + 8192  + ldsW); \
        g2lds16((gBp),                 smem + (bOff) + 0     + ldsW); \
        g2lds16((gBp) + half2,         smem + (bOff) + 8192  + ldsW); \
        g2lds16((gBp) + halfB,         smem + (bOff) + 16384 + ldsW); \
        g2lds16((gBp) + halfB + half2, smem + (bOff) + 24576 + ldsW); } while (0)

    f32x4 acc[4][4] = {};
    f32x4 oacc[4][4] = {};
    bf16x8 a0[4], a1[4], b0v[4], b1v[4];

    int aCur = 98304, aN1 = 114688, aN2 = 131072;
    int bCur = 0,     bN1 = 32768,  bN2 = 65536;

    STG6(ga, gb, aCur, bCur);
    STG6(ga + 128, gb + 128, aN1, bN1);
    WAITVM(6);
    BAR();

#pragma unroll
    for (int mf = 0; mf < 4; ++mf) a0[mf] = *(const bf16x8*)(rdA0 + aCur + mf * 2048);
#pragma unroll
    for (int nf = 0; nf < 4; ++nf) b0v[nf] = *(const bf16x8*)(rdB0 + bCur + nf * 2048);

    const int rbase = tm * 128 + wm * 64 + (lane >> 4) * 4;
    const int cbase = tn * 256 + wn * 64 + lr;

    for (int t = 0; t < 128; ++t) {
        const int t2 = t + 2;
        const bool moreS = (t2 < 128);
        const bool moreT = (t < 127);

        const char* gA2 = ga + (size_t)(t2 >> 4) * strAE + (t2 & 15) * 128;
        const char* gB2 = gb + (size_t)(t2 >> 4) * strBE + (t2 & 15) * 128;

        // ---- P0: prefetch ks1 frags (cur); stage (t+2) -> n2; MFMA ks0 (16)
#pragma unroll
        for (int mf = 0; mf < 4; ++mf) a1[mf] = *(const bf16x8*)(rdA1 + aCur + mf * 2048);
#pragma unroll
        for (int nf = 0; nf < 4; ++nf) b1v[nf] = *(const bf16x8*)(rdB1 + bCur + nf * 2048);
        if (moreS) STG6(gA2, gB2, aN2, bN2);
        __builtin_amdgcn_s_setprio(1);
#pragma unroll
        for (int mf = 0; mf < 4; ++mf)
#pragma unroll
            for (int nf = 0; nf < 4; ++nf)
                acc[mf][nf] = MFMA(a0[mf], b0v[nf], acc[mf][nf]);
        __builtin_amdgcn_s_setprio(0);

        // ---- P1: MFMA ks1 (16)
        __builtin_amdgcn_s_setprio(1);
#pragma unroll
        for (int mf = 0; mf < 4; ++mf)
#pragma unroll
            for (int nf = 0; nf < 4; ++nf)
                acc[mf][nf] = MFMA(a1[mf], b1v[nf], acc[mf][nf]);
        __builtin_amdgcn_s_setprio(0);

        // ---- boundary: t+1's loads landed (vmcnt leaves t+2's 6), all waves synced
        if (moreT) {
            if (moreS) { WAITVM(6); } else { WAITVM(0); }
            BAR();
#pragma unroll
            for (int mf = 0; mf < 4; ++mf) a0[mf] = *(const bf16x8*)(rdA0 + aN1 + mf * 2048);
#pragma unroll
            for (int nf = 0; nf < 4; ++nf) b0v[nf] = *(const bf16x8*)(rdB0 + bN1 + nf * 2048);
        }

        // ---- expert boundary: fold acc into gate-weighted out accumulator
        if ((t & 15) == 15) {
            const int e = t >> 4;
            float sc[4], tc[4];
#pragma unroll
            for (int nf = 0; nf < 4; ++nf) {
                sc[nf] = Sv[e * H2_ + cbase + nf * 16];
                tc[nf] = Tv[e * H2_ + cbase + nf * 16];
            }
#pragma unroll
            for (int mf = 0; mf < 4; ++mf) {
#pragma unroll
                for (int r = 0; r < 4; ++r) {
                    const int row = rbase + mf * 16 + r;
                    const float g = gate[(size_t)row * E_ + e];
#pragma unroll
                    for (int nf = 0; nf < 4; ++nf) {
                        float x = acc[mf][nf][r] * sc[nf] + tc[nf];
                        x = x > 0.f ? x : 0.f;
                        oacc[mf][nf][r] += g * x;
                    }
                }
            }
#pragma unroll
            for (int mf = 0; mf < 4; ++mf)
#pragma unroll
                for (int nf = 0; nf < 4; ++nf)
                    acc[mf][nf] = (f32x4){0.f, 0.f, 0.f, 0.f};
        }

        const int ta = aCur; aCur = aN1; aN1 = aN2; aN2 = ta;
        const int tb = bCur; bCur = bN1; bN1 = bN2; bN2 = tb;
    }

#pragma unroll
    for (int mf = 0; mf < 4; ++mf) {
#pragma unroll
        for (int r = 0; r < 4; ++r) {
            const int row = rbase + mf * 16 + r;
#pragma unroll
            for (int nf = 0; nf < 4; ++nf)
                outp[(size_t)row * H2_ + cbase + nf * 16] = oacc[mf][nf][r];
        }
    }
#undef STG6
}

// ---------------- launch ----------------

extern "C" void kernel_launch(void* const* d_in, const int* in_sizes, int n_in,
                              void* d_out, int out_size, void* d_ws, size_t ws_size,
                              hipStream_t stream) {
    (void)in_sizes; (void)n_in; (void)out_size; (void)ws_size;

    const float* input    = (const float*)d_in[0];
    const float* sideinfo = (const float*)d_in[1];
    const float* W1   = (const float*)d_in[2];
    const float* b1   = (const float*)d_in[3];
    const float* g1   = (const float*)d_in[4];
    const float* be1  = (const float*)d_in[5];
    const float* m1   = (const float*)d_in[6];
    const float* v1   = (const float*)d_in[7];
    const float* W2   = (const float*)d_in[8];
    const float* b2   = (const float*)d_in[9];
    const float* g2   = (const float*)d_in[10];
    const float* be2  = (const float*)d_in[11];
    const float* m2   = (const float*)d_in[12];
    const float* v2   = (const float*)d_in[13];
    const float* Wg   = (const float*)d_in[14];
    const float* bg   = (const float*)d_in[15];

    char* w = (char*)d_ws;
    size_t off = 0;
    auto carve = [&](size_t bytes) {
        void* p = w + off;
        off += (bytes + 255) & ~(size_t)255;
        return p;
    };
    ushort* Abf  = (ushort*)carve((size_t)B_ * D_ * 2);
    ushort* W1T  = (ushort*)carve((size_t)E_ * H1_ * D_ * 2);
    ushort* W2T  = (ushort*)carve((size_t)E_ * H2_ * H1_ * 2);
    ushort* hbuf = (ushort*)carve((size_t)E_ * B_ * H1_ * 2);
    float*  S1   = (float*)carve((size_t)E_ * H1_ * 4);
    float*  T1   = (float*)carve((size_t)E_ * H1_ * 4);
    float*  S2   = (float*)carve((size_t)E_ * H2_ * 4);
    float*  T2   = (float*)carve((size_t)E_ * H2_ * 4);
    float*  gatep = (float*)carve((size_t)B_ * E_ * 4);

    float* outp = (float*)d_out;

    hipFuncSetAttribute(reinterpret_cast<const void*>(&gemm8<1>),
                        hipFuncAttributeMaxDynamicSharedMemorySize, 163840);
    hipFuncSetAttribute(reinterpret_cast<const void*>(&gemm2e),
                        hipFuncAttributeMaxDynamicSharedMemorySize, 147456);

    cvt_bf16_kernel<<<4096, 256, 0, stream>>>(input, Abf, (long)B_ * D_);
    transpose_cvt_kernel<<<E_ * (D_ / 64) * (H1_ / 64), 256, 0, stream>>>(W1, W1T, D_, H1_);
    transpose_cvt_kernel<<<E_ * (H1_ / 64) * (H2_ / 64), 256, 0, stream>>>(W2, W2T, H1_, H2_);
    fold_bn_kernel<<<(E_ * H1_ + 255) / 256, 256, 0, stream>>>(g1, be1, m1, v1, b1, S1, T1, E_ * H1_);
    fold_bn_kernel<<<(E_ * H2_ + 255) / 256, 256, 0, stream>>>(g2, be2, m2, v2, b2, S2, T2, E_ * H2_);
    gate_kernel<<<B_ / 4, 256, 0, stream>>>(sideinfo, Wg, bg, gatep);

    // GEMM1: [B,D] x [D,H1] per expert -> h bf16 [E][B][H1]  (16-wave TLP variant)
    gemm8<1><<<E_ * (B_ / 256) * (H1_ / 256), 1024, 163840, stream>>>(
        Abf, W1T, 0L, S1, T1, hbuf, nullptr, nullptr, B_, H1_, D_, H1_ / 256, B_ / 256);

    // GEMM2e: expert-loop, gate-weighted, writes out exactly once (no atomics)
    gemm2e<<<(B_ / 128) * (H2_ / 256), 512, 147456, stream>>>(
        hbuf, W2T, S2, T2, gatep, outp);
}